// Round 6
// baseline (1717.385 us; speedup 1.0000x reference)
//
#include <hip/hip_runtime.h>

typedef unsigned int uint32;
typedef unsigned short ushortT;
typedef __attribute__((ext_vector_type(8))) short short8;
typedef __attribute__((ext_vector_type(4))) short short4v;
typedef __attribute__((ext_vector_type(4))) float floatx4;

#define DEV static __device__ __forceinline__

#define NN 2048
#define CC 64
#define KK 20
#define MM 32   // stage-1 candidate margin

DEV float bf2f(ushortT h) {
  union { uint32 u; float f; } c; c.u = ((uint32)h) << 16; return c.f;
}
DEV ushortT f2bf(float f) {
  union { float f; uint32 u; } c; c.f = f;
  uint32 r = c.u + 0x7FFFu + ((c.u >> 16) & 1u);   // RNE
  return (ushortT)(r >> 16);
}
DEV void split2(float v, ushortT& h, ushortT& l) {   // v == hi + lo (to ~16 mantissa bits)
  h = f2bf(v);
  l = f2bf(v - bf2f(h));
}

// ---------------------------------------------------------------- K0: sq norms (f32)
__global__ void k_sq(const float* __restrict__ x, float* __restrict__ sq) {
  int p = blockIdx.x * 256 + threadIdx.x;            // 32768 points
  const float4* row = (const float4*)(x + (size_t)p * CC);
  float s = 0.f;
#pragma unroll
  for (int q = 0; q < 16; ++q) {
    float4 v = row[q];
    s += v.x * v.x + v.y * v.y + v.z * v.z + v.w * v.w;
  }
  sq[p] = s;
}

// ---------------------------------------------------------------- K1: KNN top-20
// Stage 1: approx bf16-MFMA distances -> top-32 candidates per point.
// Stage 2: exact f64 rerank of the 32 candidates -> top-20 (matches f64 ref).
__launch_bounds__(256, 1)
__global__ void k_knn(const float* __restrict__ x, const float* __restrict__ sq,
                      int* __restrict__ idxout) {
  const int b  = blockIdx.y;
  const int i0 = blockIdx.x * 64;
  const int t  = threadIdx.x;
  const int l  = t & 63, wv = t >> 6;
  const int la = l & 15, quad = l >> 4;

  __shared__ __align__(16) ushortT sXi[64][72];
  __shared__ __align__(16) ushortT sXj[128][72];
  __shared__ float sSqi[64];
  __shared__ float sSqj[128];
  __shared__ float sQd[64][128];
  __shared__ int   sQj[64][128];
  __shared__ int   sQn[64];
  __shared__ float sTd[64];
  __shared__ int   sTj[64];
  __shared__ double sDd[64][MM];

  const float* xb = x + ((size_t)b * NN) * CC;

  for (int e = t; e < 1024; e += 256) {              // 64 rows * 16 float4
    int r = e >> 4, c4 = (e & 15) * 4;
    float4 v = ((const float4*)(xb + (size_t)(i0 + r) * CC))[e & 15];
    short4v h;
    h.x = (short)f2bf(v.x); h.y = (short)f2bf(v.y);
    h.z = (short)f2bf(v.z); h.w = (short)f2bf(v.w);
    *(short4v*)&sXi[r][c4] = h;
  }
  if (t < 64) {
    sSqi[t] = sq[b * NN + i0 + t];
    sQn[t] = 0;
    sTd[t] = 3.0e38f; sTj[t] = 0x7FFFFFFF;
  }

  float ld[MM]; int lj[MM];
#pragma unroll
  for (int s = 0; s < MM; ++s) { ld[s] = 3.0e38f; lj[s] = s; }

  __syncthreads();

  const int mt0 = (wv & 1) * 2;
  const int nt0 = (wv >> 1) * 4;

  for (int jt = 0; jt < 16; ++jt) {
    const int j0 = jt * 128;
    for (int e = t; e < 2048; e += 256) {            // 128 rows * 16 float4
      int r = e >> 4, c4 = (e & 15) * 4;
      float4 v = ((const float4*)(xb + (size_t)(j0 + r) * CC))[e & 15];
      short4v h;
      h.x = (short)f2bf(v.x); h.y = (short)f2bf(v.y);
      h.z = (short)f2bf(v.z); h.w = (short)f2bf(v.w);
      *(short4v*)&sXj[r][c4] = h;
    }
    if (t < 128) sSqj[t] = sq[b * NN + j0 + t];
    __syncthreads();

    floatx4 acc[2][4];
#pragma unroll
    for (int m = 0; m < 2; ++m)
#pragma unroll
      for (int n = 0; n < 4; ++n) acc[m][n] = (floatx4){0.f, 0.f, 0.f, 0.f};

#pragma unroll
    for (int ks = 0; ks < 2; ++ks) {
      int kof = ks * 32 + quad * 8;
      short8 a0 = *(const short8*)&sXi[(mt0    ) * 16 + la][kof];
      short8 a1 = *(const short8*)&sXi[(mt0 + 1) * 16 + la][kof];
#pragma unroll
      for (int n = 0; n < 4; ++n) {
        short8 bv = *(const short8*)&sXj[(nt0 + n) * 16 + la][kof];
        acc[0][n] = __builtin_amdgcn_mfma_f32_16x16x32_bf16(a0, bv, acc[0][n], 0, 0, 0);
        acc[1][n] = __builtin_amdgcn_mfma_f32_16x16x32_bf16(a1, bv, acc[1][n], 0, 0, 0);
      }
    }

#pragma unroll
    for (int m = 0; m < 2; ++m) {
#pragma unroll
      for (int n = 0; n < 4; ++n) {
        int jl = (nt0 + n) * 16 + la;
        float dj = sSqj[jl];
        int jg = j0 + jl;
#pragma unroll
        for (int rg = 0; rg < 4; ++rg) {
          int il = (mt0 + m) * 16 + quad * 4 + rg;
          float d = sSqi[il] + dj - 2.0f * acc[m][n][rg];
          float td = sTd[il];
          if (d < td || (d == td && jg < sTj[il])) {
            int p = atomicAdd(&sQn[il], 1);
            if (p < 128) { sQd[il][p] = d; sQj[il][p] = jg; }
          }
        }
      }
    }
    __syncthreads();

    if (t < 64) {
      int n = sQn[t]; if (n > 128) n = 128;
      for (int q = 0; q < n; ++q) {
        float d = sQd[t][q]; int j = sQj[t][q];
        if (d < ld[MM - 1] || (d == ld[MM - 1] && j < lj[MM - 1])) {
          float cd = d; int cj = j;
#pragma unroll
          for (int s = 0; s < MM; ++s) {
            bool ins = (cd < ld[s]) || (cd == ld[s] && cj < lj[s]);
            float od = ld[s]; int oj = lj[s];
            ld[s] = ins ? cd : od;  lj[s] = ins ? cj : oj;
            cd    = ins ? od : cd;  cj    = ins ? oj : cj;
          }
        }
      }
      sQn[t] = 0;
      sTd[t] = ld[MM - 1]; sTj[t] = lj[MM - 1];
    }
    __syncthreads();
  }

  // ---- stage 2: exact f64 rerank of 32 candidates per point
  if (t < 64) {
#pragma unroll
    for (int s = 0; s < MM; ++s) {
      int j = lj[s];
      sQj[t][s] = (j < 0) ? 0 : (j > NN - 1 ? NN - 1 : j);
    }
  }
  __syncthreads();

  for (int p = t; p < 64 * MM; p += 256) {
    int il = p >> 5, s = p & (MM - 1);
    int j = sQj[il][s];
    const float* xi = xb + (size_t)(i0 + il) * CC;
    const float* xj = xb + (size_t)j * CC;
    double d = 0.0;
#pragma unroll
    for (int c = 0; c < CC; ++c) {
      double df = (double)xi[c] - (double)xj[c];
      d += df * df;
    }
    sDd[il][s] = d;
  }
  __syncthreads();

  if (t < 64) {
    double bd[KK]; int bj[KK];
#pragma unroll
    for (int s = 0; s < KK; ++s) { bd[s] = 1.0e300; bj[s] = 0x7FFFFFFF; }
    for (int q = 0; q < MM; ++q) {
      double d = sDd[t][q]; int j = sQj[t][q];
      if (d < bd[KK - 1] || (d == bd[KK - 1] && j < bj[KK - 1])) {
        double cd = d; int cj = j;
#pragma unroll
        for (int s = 0; s < KK; ++s) {
          bool ins = (cd < bd[s]) || (cd == bd[s] && cj < bj[s]);
          double od = bd[s]; int oj = bj[s];
          bd[s] = ins ? cd : od;  bj[s] = ins ? cj : oj;
          cd    = ins ? od : cd;  cj    = ins ? oj : cj;
        }
      }
    }
    size_t base = ((size_t)(b * NN + i0 + t)) * KK;
#pragma unroll
    for (int s = 0; s < KK; ++s) idxout[base + s] = bj[s];
  }
}

// ---------------------------------------------------------------- K2: edge MLP + max-agg (near-f32-exact)
__launch_bounds__(256, 1)
__global__ void k_mlp(const float* __restrict__ x, const int* __restrict__ idx,
                      const float* __restrict__ w1, const float* __restrict__ b1,
                      const float* __restrict__ w2, const float* __restrict__ b2,
                      const float* __restrict__ w3, const float* __restrict__ b3,
                      float* __restrict__ agg) {
  const int b  = blockIdx.y;
  const int i0 = blockIdx.x * 8;
  const int t  = threadIdx.x;
  const int l  = t & 63, wv = t >> 6;
  const int la = l & 15, quad = l >> 4;
  const int wm = wv >> 1, wn = wv & 1;

  __shared__ __align__(16) char sm[152448];
  ushortT (*sW1)[136] = (ushortT(*)[136])(sm + 0);       // [n][k<128]: W1a|W1b
  ushortT (*sW2)[72]  = (ushortT(*)[72])(sm + 17408);
  ushortT (*sW3)[72]  = (ushortT(*)[72])(sm + 26624);
  ushortT (*sXi)[72]  = (ushortT(*)[72])(sm + 35840);    // later: sH2H
  ushortT (*sDH)[72]  = (ushortT(*)[72])(sm + 58880);    // later: sH2L
  ushortT (*sDL)[72]  = (ushortT(*)[72])(sm + 81920);
  ushortT (*sH1H)[72] = (ushortT(*)[72])(sm + 104960);
  ushortT (*sH1L)[72] = (ushortT(*)[72])(sm + 128000);
  float   (*sH3)[68]  = (float(*)[68])  (sm + 104960);   // aliases H1H+H1L (43520 <= 46080)
  float* sB1 = (float*)(sm + 151040);
  float* sB2 = (float*)(sm + 151296);
  float* sB3 = (float*)(sm + 151552);
  int*   sJ  = (int*)  (sm + 151808);                    // 160 ints

  for (int e = t; e < 8192; e += 256) {                  // W1: exact bf16
    int k = e >> 6, n = e & 63;
    sW1[n][k] = f2bf(w1[e]);
  }
  for (int e = t; e < 4096; e += 256) {
    int k = e >> 6, n = e & 63;
    sW2[n][k] = f2bf(w2[e]);
    sW3[n][k] = f2bf(w3[e]);
  }
  if (t < 64) { sB1[t] = b1[t]; sB2[t] = b2[t]; sB3[t] = b3[t]; }
  if (t < 160) {
    int p = t / 20, kk = t - p * 20;
    int v = idx[((size_t)(b * NN + i0 + p)) * KK + kk];
    v = v < 0 ? 0 : (v > (NN - 1) ? (NN - 1) : v);
    sJ[t] = v;
  }
  __syncthreads();

  const float* xb = x + ((size_t)b * NN) * CC;
  for (int e = t; e < 2560; e += 256) {                  // 160 rows * 16 float4
    int r = e >> 4, c4g = e & 15, c4 = c4g * 4;
    int p = r / 20;
    float4 vi = ((const float4*)(xb + (size_t)(i0 + p) * CC))[c4g];
    float4 vj = ((const float4*)(xb + (size_t)sJ[r] * CC))[c4g];
    short4v hi, dh, dl;
    ushortT hh, ll;
    hi.x = (short)f2bf(vi.x); hi.y = (short)f2bf(vi.y);
    hi.z = (short)f2bf(vi.z); hi.w = (short)f2bf(vi.w);
    split2(vj.x - vi.x, hh, ll); dh.x = (short)hh; dl.x = (short)ll;
    split2(vj.y - vi.y, hh, ll); dh.y = (short)hh; dl.y = (short)ll;
    split2(vj.z - vi.z, hh, ll); dh.z = (short)hh; dl.z = (short)ll;
    split2(vj.w - vi.w, hh, ll); dh.w = (short)hh; dl.w = (short)ll;
    *(short4v*)&sXi[r][c4] = hi;
    *(short4v*)&sDH[r][c4] = dh;
    *(short4v*)&sDL[r][c4] = dl;
  }
  __syncthreads();

  // ---- layer 1: acc = xi@W1a + dH@W1b + dL@W1b  -> relu -> split -> sH1H/sH1L
  {
    short8 bA[2][2], bB[2][2];
#pragma unroll
    for (int n2 = 0; n2 < 2; ++n2)
#pragma unroll
      for (int ks = 0; ks < 2; ++ks) {
        bA[n2][ks] = *(const short8*)&sW1[(wn * 2 + n2) * 16 + la][ks * 32 + quad * 8];
        bB[n2][ks] = *(const short8*)&sW1[(wn * 2 + n2) * 16 + la][64 + ks * 32 + quad * 8];
      }
    for (int m5 = 0; m5 < 5; ++m5) {
      int mt = wm * 5 + m5;
      floatx4 a0 = (floatx4){0.f,0.f,0.f,0.f}, a1 = (floatx4){0.f,0.f,0.f,0.f};
#pragma unroll
      for (int ks = 0; ks < 2; ++ks) {
        int kof = ks * 32 + quad * 8;
        short8 aXi = *(const short8*)&sXi[mt * 16 + la][kof];
        short8 aDH = *(const short8*)&sDH[mt * 16 + la][kof];
        short8 aDL = *(const short8*)&sDL[mt * 16 + la][kof];
        a0 = __builtin_amdgcn_mfma_f32_16x16x32_bf16(aXi, bA[0][ks], a0, 0, 0, 0);
        a0 = __builtin_amdgcn_mfma_f32_16x16x32_bf16(aDH, bB[0][ks], a0, 0, 0, 0);
        a0 = __builtin_amdgcn_mfma_f32_16x16x32_bf16(aDL, bB[0][ks], a0, 0, 0, 0);
        a1 = __builtin_amdgcn_mfma_f32_16x16x32_bf16(aXi, bA[1][ks], a1, 0, 0, 0);
        a1 = __builtin_amdgcn_mfma_f32_16x16x32_bf16(aDH, bB[1][ks], a1, 0, 0, 0);
        a1 = __builtin_amdgcn_mfma_f32_16x16x32_bf16(aDL, bB[1][ks], a1, 0, 0, 0);
      }
      int n0c = (wn * 2) * 16 + la, n1c = (wn * 2 + 1) * 16 + la;
#pragma unroll
      for (int rg = 0; rg < 4; ++rg) {
        int r = mt * 16 + quad * 4 + rg;
        ushortT hh, ll;
        split2(fmaxf(a0[rg] + sB1[n0c], 0.f), hh, ll);
        sH1H[r][n0c] = hh; sH1L[r][n0c] = ll;
        split2(fmaxf(a1[rg] + sB1[n1c], 0.f), hh, ll);
        sH1H[r][n1c] = hh; sH1L[r][n1c] = ll;
      }
    }
  }
  __syncthreads();

  // ---- layer 2: (h1H + h1L) @ W2 -> relu -> split -> sH2H/sH2L (alias sXi/sDH)
  ushortT (*sH2H)[72] = sXi;
  ushortT (*sH2L)[72] = sDH;
  {
    short8 bf[2][2];
#pragma unroll
    for (int n2 = 0; n2 < 2; ++n2)
#pragma unroll
      for (int ks = 0; ks < 2; ++ks)
        bf[n2][ks] = *(const short8*)&sW2[(wn * 2 + n2) * 16 + la][ks * 32 + quad * 8];
    for (int m5 = 0; m5 < 5; ++m5) {
      int mt = wm * 5 + m5;
      floatx4 a0 = (floatx4){0.f,0.f,0.f,0.f}, a1 = (floatx4){0.f,0.f,0.f,0.f};
#pragma unroll
      for (int ks = 0; ks < 2; ++ks) {
        int kof = ks * 32 + quad * 8;
        short8 aH = *(const short8*)&sH1H[mt * 16 + la][kof];
        short8 aL = *(const short8*)&sH1L[mt * 16 + la][kof];
        a0 = __builtin_amdgcn_mfma_f32_16x16x32_bf16(aH, bf[0][ks], a0, 0, 0, 0);
        a0 = __builtin_amdgcn_mfma_f32_16x16x32_bf16(aL, bf[0][ks], a0, 0, 0, 0);
        a1 = __builtin_amdgcn_mfma_f32_16x16x32_bf16(aH, bf[1][ks], a1, 0, 0, 0);
        a1 = __builtin_amdgcn_mfma_f32_16x16x32_bf16(aL, bf[1][ks], a1, 0, 0, 0);
      }
      int n0c = (wn * 2) * 16 + la, n1c = (wn * 2 + 1) * 16 + la;
#pragma unroll
      for (int rg = 0; rg < 4; ++rg) {
        int r = mt * 16 + quad * 4 + rg;
        ushortT hh, ll;
        split2(fmaxf(a0[rg] + sB2[n0c], 0.f), hh, ll);
        sH2H[r][n0c] = hh; sH2L[r][n0c] = ll;
        split2(fmaxf(a1[rg] + sB2[n1c], 0.f), hh, ll);
        sH2H[r][n1c] = hh; sH2L[r][n1c] = ll;
      }
    }
  }
  __syncthreads();

  // ---- layer 3: (h2H + h2L) @ W3 + b3 -> f32 sH3 (alias sH1 space)
  {
    short8 bf[2][2];
#pragma unroll
    for (int n2 = 0; n2 < 2; ++n2)
#pragma unroll
      for (int ks = 0; ks < 2; ++ks)
        bf[n2][ks] = *(const short8*)&sW3[(wn * 2 + n2) * 16 + la][ks * 32 + quad * 8];
    for (int m5 = 0; m5 < 5; ++m5) {
      int mt = wm * 5 + m5;
      floatx4 a0 = (floatx4){0.f,0.f,0.f,0.f}, a1 = (floatx4){0.f,0.f,0.f,0.f};
#pragma unroll
      for (int ks = 0; ks < 2; ++ks) {
        int kof = ks * 32 + quad * 8;
        short8 aH = *(const short8*)&sH2H[mt * 16 + la][kof];
        short8 aL = *(const short8*)&sH2L[mt * 16 + la][kof];
        a0 = __builtin_amdgcn_mfma_f32_16x16x32_bf16(aH, bf[0][ks], a0, 0, 0, 0);
        a0 = __builtin_amdgcn_mfma_f32_16x16x32_bf16(aL, bf[0][ks], a0, 0, 0, 0);
        a1 = __builtin_amdgcn_mfma_f32_16x16x32_bf16(aH, bf[1][ks], a1, 0, 0, 0);
        a1 = __builtin_amdgcn_mfma_f32_16x16x32_bf16(aL, bf[1][ks], a1, 0, 0, 0);
      }
      int n0c = (wn * 2) * 16 + la, n1c = (wn * 2 + 1) * 16 + la;
#pragma unroll
      for (int rg = 0; rg < 4; ++rg) {
        int r = mt * 16 + quad * 4 + rg;
        sH3[r][n0c] = a0[rg] + sB3[n0c];
        sH3[r][n1c] = a1[rg] + sB3[n1c];
      }
    }
  }
  __syncthreads();

  for (int e = t; e < 512; e += 256) {                   // max over K=20, f32
    int p = e >> 6, c = e & 63;
    float m = -3.0e38f;
#pragma unroll
    for (int k = 0; k < KK; ++k) m = fmaxf(m, sH3[p * 20 + k][c]);
    agg[((size_t)(b * NN + i0 + p)) * CC + c] = m;
  }
}

// ---------------------------------------------------------------- K3: SE (f32)
__global__ void k_se(const float* __restrict__ agg, const float* __restrict__ sew1,
                     const float* __restrict__ sew2, float* __restrict__ y) {
  int b = blockIdx.x, t = threadIdx.x;
  int c = t & 63, q = t >> 6;
  __shared__ float part[4][64];
  __shared__ float sv[64];
  __shared__ float hid[4];
  const float* ab = agg + ((size_t)b * NN) * CC;
  float s = 0.f;
  for (int n = q * 512; n < q * 512 + 512; ++n) s += ab[(size_t)n * CC + c];
  part[q][c] = s;
  __syncthreads();
  if (t < 64) sv[t] = (part[0][t] + part[1][t] + part[2][t] + part[3][t]) * (1.f / 2048.f);
  __syncthreads();
  if (t < 4) {
    float a = 0.f;
    for (int cc = 0; cc < 64; ++cc) a += sv[cc] * sew1[cc * 4 + t];
    hid[t] = fmaxf(a, 0.f);
  }
  __syncthreads();
  if (t < 64) {
    float a = 0.f;
#pragma unroll
    for (int h = 0; h < 4; ++h) a += hid[h] * sew2[h * 64 + t];
    y[b * 64 + t] = 1.f / (1.f + expf(-a));
  }
}

// ---------------------------------------------------------------- K4: per-point stats (f32)
__global__ void k_stats(const float* __restrict__ agg, const float* __restrict__ y,
                        float* __restrict__ ycat) {
  int t = threadIdx.x;
  int gid = blockIdx.x * 4 + (t >> 6);
  int l = t & 63;
  int b = gid >> 11, i = gid & 2047;
  float v = agg[(size_t)gid * CC + l] * y[b * 64 + l];
  float s = v, mx = v;
#pragma unroll
  for (int off = 32; off > 0; off >>= 1) {
    s += __shfl_xor(s, off);
    mx = fmaxf(mx, __shfl_xor(mx, off));
  }
  if (l == 0) {
    ycat[b * 2 * NN + i] = s * (1.f / 64.f);
    ycat[b * 2 * NN + NN + i] = mx;
  }
}

// ---------------------------------------------------------------- K5: conv7 att + add (f32 out)
__global__ void k_final(const float* __restrict__ agg, const float* __restrict__ y,
                        const float* __restrict__ ycat, const float* __restrict__ saw,
                        const float* __restrict__ x, float* __restrict__ out) {
  int e = blockIdx.x * 256 + threadIdx.x;
  int ifl = e >> 6, c = e & 63;
  int b = ifl >> 11, i = ifl & 2047;
  float a = 0.f;
#pragma unroll
  for (int w = 0; w < 7; ++w) {
    int ii = i + w - 3;
    if (ii >= 0 && ii < NN) {
      a += ycat[b * 2 * NN + ii] * saw[w];
      a += ycat[b * 2 * NN + NN + ii] * saw[7 + w];
    }
  }
  float att = 1.f / (1.f + expf(-a));
  out[e] = agg[(size_t)ifl * CC + c] * y[b * 64 + c] * att + x[(size_t)e];
}

// ----------------------------------------------------------------
extern "C" void kernel_launch(void* const* d_in, const int* in_sizes, int n_in,
                              void* d_out, int out_size, void* d_ws, size_t ws_size,
                              hipStream_t stream) {
  const float* x    = (const float*)d_in[0];
  const float* w1   = (const float*)d_in[3];
  const float* b1   = (const float*)d_in[4];
  const float* w2   = (const float*)d_in[5];
  const float* b2   = (const float*)d_in[6];
  const float* w3   = (const float*)d_in[7];
  const float* b3   = (const float*)d_in[8];
  const float* sew1 = (const float*)d_in[9];
  const float* sew2 = (const float*)d_in[10];
  const float* saw  = (const float*)d_in[11];
  float* out = (float*)d_out;

  char* ws = (char*)d_ws;
  float* sq   = (float*)(ws);                              // 131072 B
  int*   idx  = (int*)  (ws + 131072);                     // 2621440 B
  float* agg  = (float*)(ws + 131072 + 2621440);           // 8388608 B (f32)
  float* y    = (float*)(ws + 11141120);                   // 4096 B
  float* ycat = (float*)(ws + 11145216);                   // 262144 B -> total 11407360 B

  k_sq   <<<128,            256, 0, stream>>>(x, sq);
  k_knn  <<<dim3(32, 16),   256, 0, stream>>>(x, sq, idx);
  k_mlp  <<<dim3(256, 16),  256, 0, stream>>>(x, idx, w1, b1, w2, b2, w3, b3, agg);
  k_se   <<<16,             256, 0, stream>>>(agg, sew1, sew2, y);
  k_stats<<<8192,           256, 0, stream>>>(agg, y, ycat);
  k_final<<<8192,           256, 0, stream>>>(agg, y, ycat, saw, x, out);
}

// Round 7
// 769.748 us; speedup vs baseline: 2.2311x; 2.2311x over previous
//
#include <hip/hip_runtime.h>

typedef unsigned int uint32;
typedef unsigned long long uint64;
typedef unsigned short ushortT;
typedef __attribute__((ext_vector_type(8))) short short8;
typedef __attribute__((ext_vector_type(4))) short short4v;
typedef __attribute__((ext_vector_type(4))) float floatx4;

#define DEV static __device__ __forceinline__

#define NN 2048
#define CC 64
#define KK 20
#define DEPTH 28          // per-thread candidate list depth (4 threads/point -> 112 union)

DEV float bf2f(ushortT h) {
  union { uint32 u; float f; } c; c.u = ((uint32)h) << 16; return c.f;
}
DEV ushortT f2bf(float f) {
  union { float f; uint32 u; } c; c.f = f;
  uint32 r = c.u + 0x7FFFu + ((c.u >> 16) & 1u);   // RNE
  return (ushortT)(r >> 16);
}
DEV void split2(float v, ushortT& h, ushortT& l) {
  h = f2bf(v);
  l = f2bf(v - bf2f(h));
}

// ---------------------------------------------------------------- K0: sq norms (f32)
__global__ void k_sq(const float* __restrict__ x, float* __restrict__ sq) {
  int p = blockIdx.x * 256 + threadIdx.x;
  const float4* row = (const float4*)(x + (size_t)p * CC);
  float s = 0.f;
#pragma unroll
  for (int q = 0; q < 16; ++q) {
    float4 v = row[q];
    s += v.x * v.x + v.y * v.y + v.z * v.z + v.w * v.w;
  }
  sq[p] = s;
}

// ---------------------------------------------------------------- K1: KNN top-20 (parallel selection)
// Stage 1: MFMA approx distances -> packed u32 keys in LDS; 4 threads/point keep
// register top-28 of disjoint subsets (union=112 is a superset of true top-20).
// Stage 2: cooperative exact-f64 rerank (16-lane groups, coalesced loads) -> u64
// keys in LDS; owner lane selects final (d,j)-ordered top-20.
__launch_bounds__(256, 2)
__global__ void k_knn(const float* __restrict__ x, const float* __restrict__ sq,
                      int* __restrict__ idxout) {
  const int b  = blockIdx.y;
  const int i0 = blockIdx.x * 64;
  const int t  = threadIdx.x;
  const int l  = t & 63, wv = t >> 6;
  const int la = l & 15, quad = l >> 4;
  const int pp = t >> 2, ss = t & 3;          // selection: point, subset

  __shared__ __align__(16) char sm[62208];
  ushortT (*sXi)[72]  = (ushortT(*)[72])(sm);            // 9216
  float*   sSqi       = (float*)(sm + 9216);             // 256
  float*   sSqj       = (float*)(sm + 9472);             // 512
  ushortT (*sXj)[72]  = (ushortT(*)[72])(sm + 9984);     // 18432 -> 28416
  uint32  (*sKey)[132]= (uint32(*)[132])(sm + 28416);    // 33792 -> 62208
  uint64  (*sK64)[113]= (uint64(*)[113])(sm);            // 57856, aliases all above (used last)

  const float* xb = x + ((size_t)b * NN) * CC;

  for (int e = t; e < 1024; e += 256) {                  // stage Xi (bf16)
    int r = e >> 4, c4 = (e & 15) * 4;
    float4 v = ((const float4*)(xb + (size_t)(i0 + r) * CC))[e & 15];
    short4v h;
    h.x = (short)f2bf(v.x); h.y = (short)f2bf(v.y);
    h.z = (short)f2bf(v.z); h.w = (short)f2bf(v.w);
    *(short4v*)&sXi[r][c4] = h;
  }
  if (t < 64) sSqi[t] = sq[b * NN + i0 + t];

  uint32 lst[DEPTH];
#pragma unroll
  for (int s = 0; s < DEPTH; ++s) lst[s] = 0xFFFFFFFFu;

  const int mt0 = (wv & 1) * 2;
  const int nt0 = (wv >> 1) * 4;

  __syncthreads();

  for (int jt = 0; jt < 16; ++jt) {
    const int j0 = jt * 128;
    for (int e = t; e < 2048; e += 256) {                // stage Xj (bf16)
      int r = e >> 4, c4 = (e & 15) * 4;
      float4 v = ((const float4*)(xb + (size_t)(j0 + r) * CC))[e & 15];
      short4v h;
      h.x = (short)f2bf(v.x); h.y = (short)f2bf(v.y);
      h.z = (short)f2bf(v.z); h.w = (short)f2bf(v.w);
      *(short4v*)&sXj[r][c4] = h;
    }
    if (t < 128) sSqj[t] = sq[b * NN + j0 + t];
    __syncthreads();                                     // also: prior scans done

    floatx4 acc[2][4];
#pragma unroll
    for (int m = 0; m < 2; ++m)
#pragma unroll
      for (int n = 0; n < 4; ++n) acc[m][n] = (floatx4){0.f, 0.f, 0.f, 0.f};

#pragma unroll
    for (int ks = 0; ks < 2; ++ks) {
      int kof = ks * 32 + quad * 8;
      short8 a0 = *(const short8*)&sXi[(mt0    ) * 16 + la][kof];
      short8 a1 = *(const short8*)&sXi[(mt0 + 1) * 16 + la][kof];
#pragma unroll
      for (int n = 0; n < 4; ++n) {
        short8 bv = *(const short8*)&sXj[(nt0 + n) * 16 + la][kof];
        acc[0][n] = __builtin_amdgcn_mfma_f32_16x16x32_bf16(a0, bv, acc[0][n], 0, 0, 0);
        acc[1][n] = __builtin_amdgcn_mfma_f32_16x16x32_bf16(a1, bv, acc[1][n], 0, 0, 0);
      }
    }

#pragma unroll
    for (int m = 0; m < 2; ++m) {
#pragma unroll
      for (int n = 0; n < 4; ++n) {
        int jl = (nt0 + n) * 16 + la;
        float dj = sSqj[jl];
        uint32 jg = (uint32)(j0 + jl);
#pragma unroll
        for (int rg = 0; rg < 4; ++rg) {
          int il = (mt0 + m) * 16 + quad * 4 + rg;
          float d = fmaxf(sSqi[il] + dj - 2.0f * acc[m][n][rg], 0.f);
          sKey[il][jl] = (__float_as_uint(d) & 0xFFFFF800u) | jg;
        }
      }
    }
    __syncthreads();

    // parallel selection: thread (pp,ss) scans cols ss,ss+4,... of row pp
#pragma unroll 4
    for (int k = 0; k < 32; ++k) {
      uint32 c = sKey[pp][ss + 4 * k];
      if (c < lst[DEPTH - 1]) {
#pragma unroll
        for (int s = 0; s < DEPTH; ++s) {
          uint32 o = lst[s];
          bool ins = c < o;
          lst[s] = ins ? c : o;
          c      = ins ? o : c;
        }
      }
    }
    // next tile's Xj/sqj staging overlaps other threads' scans (disjoint regions)
  }
  __syncthreads();                                       // all scans done; alias region free

  // dump candidates (low u32 of the u64 slot)
#pragma unroll
  for (int q = 0; q < DEPTH; ++q)
    sK64[pp][ss * DEPTH + q] = (uint64)lst[q];
  __syncthreads();

  // cooperative exact-f64 rerank: 16 groups of 16 lanes; 448 pairs each
  {
    const int grp = t >> 4;                               // 0..15
    const int lg  = t & 15;
    for (int it = 0; it < 448; ++it) {
      int pair = grp + 16 * it;                           // 0..7167
      int p = pair / 112, q = pair - p * 112;
      uint32 cand = (uint32)sK64[p][q];
      int j = (int)(cand & 2047u);
      float4 vi = ((const float4*)(xb + (size_t)(i0 + p) * CC))[lg];
      float4 vj = ((const float4*)(xb + (size_t)j * CC))[lg];
      double d;
      {
        double df0 = (double)vi.x - (double)vj.x;
        double df1 = (double)vi.y - (double)vj.y;
        double df2 = (double)vi.z - (double)vj.z;
        double df3 = (double)vi.w - (double)vj.w;
        d = df0 * df0 + df1 * df1 + df2 * df2 + df3 * df3;
      }
#pragma unroll
      for (int off = 8; off > 0; off >>= 1)
        d += __shfl_xor(d, off, 16);
      if (lg == 0) {
        uint64 bits = (uint64)__double_as_longlong(d);    // d >= 0 -> order-preserving
        sK64[p][q] = (bits & ~2047ULL) | (uint64)j;
      }
    }
  }
  __syncthreads();

  if (t < 64) {                                          // final top-20 of 112 (u64 keys)
    uint64 bl[KK];
#pragma unroll
    for (int s = 0; s < KK; ++s) bl[s] = ~0ULL;
    for (int q = 0; q < 112; ++q) {
      uint64 c = sK64[t][q];
      if (c < bl[KK - 1]) {
#pragma unroll
        for (int s = 0; s < KK; ++s) {
          uint64 o = bl[s];
          bool ins = c < o;
          bl[s] = ins ? c : o;
          c     = ins ? o : c;
        }
      }
    }
    size_t base = ((size_t)(b * NN + i0 + t)) * KK;
#pragma unroll
    for (int s = 0; s < KK; ++s) idxout[base + s] = (int)(bl[s] & 2047ULL);
  }
}

// ---------------------------------------------------------------- K2: edge MLP + max-agg (near-f32-exact)
__launch_bounds__(256, 1)
__global__ void k_mlp(const float* __restrict__ x, const int* __restrict__ idx,
                      const float* __restrict__ w1, const float* __restrict__ b1,
                      const float* __restrict__ w2, const float* __restrict__ b2,
                      const float* __restrict__ w3, const float* __restrict__ b3,
                      float* __restrict__ agg) {
  const int b  = blockIdx.y;
  const int i0 = blockIdx.x * 8;
  const int t  = threadIdx.x;
  const int l  = t & 63, wv = t >> 6;
  const int la = l & 15, quad = l >> 4;
  const int wm = wv >> 1, wn = wv & 1;

  __shared__ __align__(16) char sm[152448];
  ushortT (*sW1)[136] = (ushortT(*)[136])(sm + 0);
  ushortT (*sW2)[72]  = (ushortT(*)[72])(sm + 17408);
  ushortT (*sW3)[72]  = (ushortT(*)[72])(sm + 26624);
  ushortT (*sXi)[72]  = (ushortT(*)[72])(sm + 35840);
  ushortT (*sDH)[72]  = (ushortT(*)[72])(sm + 58880);
  ushortT (*sDL)[72]  = (ushortT(*)[72])(sm + 81920);
  ushortT (*sH1H)[72] = (ushortT(*)[72])(sm + 104960);
  ushortT (*sH1L)[72] = (ushortT(*)[72])(sm + 128000);
  float   (*sH3)[68]  = (float(*)[68])  (sm + 104960);
  float* sB1 = (float*)(sm + 151040);
  float* sB2 = (float*)(sm + 151296);
  float* sB3 = (float*)(sm + 151552);
  int*   sJ  = (int*)  (sm + 151808);

  for (int e = t; e < 8192; e += 256) {
    int k = e >> 6, n = e & 63;
    sW1[n][k] = f2bf(w1[e]);
  }
  for (int e = t; e < 4096; e += 256) {
    int k = e >> 6, n = e & 63;
    sW2[n][k] = f2bf(w2[e]);
    sW3[n][k] = f2bf(w3[e]);
  }
  if (t < 64) { sB1[t] = b1[t]; sB2[t] = b2[t]; sB3[t] = b3[t]; }
  if (t < 160) {
    int p = t / 20, kk = t - p * 20;
    int v = idx[((size_t)(b * NN + i0 + p)) * KK + kk];
    v = v < 0 ? 0 : (v > (NN - 1) ? (NN - 1) : v);
    sJ[t] = v;
  }
  __syncthreads();

  const float* xb = x + ((size_t)b * NN) * CC;
  for (int e = t; e < 2560; e += 256) {
    int r = e >> 4, c4g = e & 15, c4 = c4g * 4;
    int p = r / 20;
    float4 vi = ((const float4*)(xb + (size_t)(i0 + p) * CC))[c4g];
    float4 vj = ((const float4*)(xb + (size_t)sJ[r] * CC))[c4g];
    short4v hi, dh, dl;
    ushortT hh, ll;
    hi.x = (short)f2bf(vi.x); hi.y = (short)f2bf(vi.y);
    hi.z = (short)f2bf(vi.z); hi.w = (short)f2bf(vi.w);
    split2(vj.x - vi.x, hh, ll); dh.x = (short)hh; dl.x = (short)ll;
    split2(vj.y - vi.y, hh, ll); dh.y = (short)hh; dl.y = (short)ll;
    split2(vj.z - vi.z, hh, ll); dh.z = (short)hh; dl.z = (short)ll;
    split2(vj.w - vi.w, hh, ll); dh.w = (short)hh; dl.w = (short)ll;
    *(short4v*)&sXi[r][c4] = hi;
    *(short4v*)&sDH[r][c4] = dh;
    *(short4v*)&sDL[r][c4] = dl;
  }
  __syncthreads();

  // ---- layer 1
  {
    short8 bA[2][2], bB[2][2];
#pragma unroll
    for (int n2 = 0; n2 < 2; ++n2)
#pragma unroll
      for (int ks = 0; ks < 2; ++ks) {
        bA[n2][ks] = *(const short8*)&sW1[(wn * 2 + n2) * 16 + la][ks * 32 + quad * 8];
        bB[n2][ks] = *(const short8*)&sW1[(wn * 2 + n2) * 16 + la][64 + ks * 32 + quad * 8];
      }
    for (int m5 = 0; m5 < 5; ++m5) {
      int mt = wm * 5 + m5;
      floatx4 a0 = (floatx4){0.f,0.f,0.f,0.f}, a1 = (floatx4){0.f,0.f,0.f,0.f};
#pragma unroll
      for (int ks = 0; ks < 2; ++ks) {
        int kof = ks * 32 + quad * 8;
        short8 aXi = *(const short8*)&sXi[mt * 16 + la][kof];
        short8 aDH = *(const short8*)&sDH[mt * 16 + la][kof];
        short8 aDL = *(const short8*)&sDL[mt * 16 + la][kof];
        a0 = __builtin_amdgcn_mfma_f32_16x16x32_bf16(aXi, bA[0][ks], a0, 0, 0, 0);
        a0 = __builtin_amdgcn_mfma_f32_16x16x32_bf16(aDH, bB[0][ks], a0, 0, 0, 0);
        a0 = __builtin_amdgcn_mfma_f32_16x16x32_bf16(aDL, bB[0][ks], a0, 0, 0, 0);
        a1 = __builtin_amdgcn_mfma_f32_16x16x32_bf16(aXi, bA[1][ks], a1, 0, 0, 0);
        a1 = __builtin_amdgcn_mfma_f32_16x16x32_bf16(aDH, bB[1][ks], a1, 0, 0, 0);
        a1 = __builtin_amdgcn_mfma_f32_16x16x32_bf16(aDL, bB[1][ks], a1, 0, 0, 0);
      }
      int n0c = (wn * 2) * 16 + la, n1c = (wn * 2 + 1) * 16 + la;
#pragma unroll
      for (int rg = 0; rg < 4; ++rg) {
        int r = mt * 16 + quad * 4 + rg;
        ushortT hh, ll;
        split2(fmaxf(a0[rg] + sB1[n0c], 0.f), hh, ll);
        sH1H[r][n0c] = hh; sH1L[r][n0c] = ll;
        split2(fmaxf(a1[rg] + sB1[n1c], 0.f), hh, ll);
        sH1H[r][n1c] = hh; sH1L[r][n1c] = ll;
      }
    }
  }
  __syncthreads();

  // ---- layer 2
  ushortT (*sH2H)[72] = sXi;
  ushortT (*sH2L)[72] = sDH;
  {
    short8 bf[2][2];
#pragma unroll
    for (int n2 = 0; n2 < 2; ++n2)
#pragma unroll
      for (int ks = 0; ks < 2; ++ks)
        bf[n2][ks] = *(const short8*)&sW2[(wn * 2 + n2) * 16 + la][ks * 32 + quad * 8];
    for (int m5 = 0; m5 < 5; ++m5) {
      int mt = wm * 5 + m5;
      floatx4 a0 = (floatx4){0.f,0.f,0.f,0.f}, a1 = (floatx4){0.f,0.f,0.f,0.f};
#pragma unroll
      for (int ks = 0; ks < 2; ++ks) {
        int kof = ks * 32 + quad * 8;
        short8 aH = *(const short8*)&sH1H[mt * 16 + la][kof];
        short8 aL = *(const short8*)&sH1L[mt * 16 + la][kof];
        a0 = __builtin_amdgcn_mfma_f32_16x16x32_bf16(aH, bf[0][ks], a0, 0, 0, 0);
        a0 = __builtin_amdgcn_mfma_f32_16x16x32_bf16(aL, bf[0][ks], a0, 0, 0, 0);
        a1 = __builtin_amdgcn_mfma_f32_16x16x32_bf16(aH, bf[1][ks], a1, 0, 0, 0);
        a1 = __builtin_amdgcn_mfma_f32_16x16x32_bf16(aL, bf[1][ks], a1, 0, 0, 0);
      }
      int n0c = (wn * 2) * 16 + la, n1c = (wn * 2 + 1) * 16 + la;
#pragma unroll
      for (int rg = 0; rg < 4; ++rg) {
        int r = mt * 16 + quad * 4 + rg;
        ushortT hh, ll;
        split2(fmaxf(a0[rg] + sB2[n0c], 0.f), hh, ll);
        sH2H[r][n0c] = hh; sH2L[r][n0c] = ll;
        split2(fmaxf(a1[rg] + sB2[n1c], 0.f), hh, ll);
        sH2H[r][n1c] = hh; sH2L[r][n1c] = ll;
      }
    }
  }
  __syncthreads();

  // ---- layer 3
  {
    short8 bf[2][2];
#pragma unroll
    for (int n2 = 0; n2 < 2; ++n2)
#pragma unroll
      for (int ks = 0; ks < 2; ++ks)
        bf[n2][ks] = *(const short8*)&sW3[(wn * 2 + n2) * 16 + la][ks * 32 + quad * 8];
    for (int m5 = 0; m5 < 5; ++m5) {
      int mt = wm * 5 + m5;
      floatx4 a0 = (floatx4){0.f,0.f,0.f,0.f}, a1 = (floatx4){0.f,0.f,0.f,0.f};
#pragma unroll
      for (int ks = 0; ks < 2; ++ks) {
        int kof = ks * 32 + quad * 8;
        short8 aH = *(const short8*)&sH2H[mt * 16 + la][kof];
        short8 aL = *(const short8*)&sH2L[mt * 16 + la][kof];
        a0 = __builtin_amdgcn_mfma_f32_16x16x32_bf16(aH, bf[0][ks], a0, 0, 0, 0);
        a0 = __builtin_amdgcn_mfma_f32_16x16x32_bf16(aL, bf[0][ks], a0, 0, 0, 0);
        a1 = __builtin_amdgcn_mfma_f32_16x16x32_bf16(aH, bf[1][ks], a1, 0, 0, 0);
        a1 = __builtin_amdgcn_mfma_f32_16x16x32_bf16(aL, bf[1][ks], a1, 0, 0, 0);
      }
      int n0c = (wn * 2) * 16 + la, n1c = (wn * 2 + 1) * 16 + la;
#pragma unroll
      for (int rg = 0; rg < 4; ++rg) {
        int r = mt * 16 + quad * 4 + rg;
        sH3[r][n0c] = a0[rg] + sB3[n0c];
        sH3[r][n1c] = a1[rg] + sB3[n1c];
      }
    }
  }
  __syncthreads();

  for (int e = t; e < 512; e += 256) {
    int p = e >> 6, c = e & 63;
    float m = -3.0e38f;
#pragma unroll
    for (int k = 0; k < KK; ++k) m = fmaxf(m, sH3[p * 20 + k][c]);
    agg[((size_t)(b * NN + i0 + p)) * CC + c] = m;
  }
}

// ---------------------------------------------------------------- K3: SE (f32)
__global__ void k_se(const float* __restrict__ agg, const float* __restrict__ sew1,
                     const float* __restrict__ sew2, float* __restrict__ y) {
  int b = blockIdx.x, t = threadIdx.x;
  int c = t & 63, q = t >> 6;
  __shared__ float part[4][64];
  __shared__ float sv[64];
  __shared__ float hid[4];
  const float* ab = agg + ((size_t)b * NN) * CC;
  float s = 0.f;
  for (int n = q * 512; n < q * 512 + 512; ++n) s += ab[(size_t)n * CC + c];
  part[q][c] = s;
  __syncthreads();
  if (t < 64) sv[t] = (part[0][t] + part[1][t] + part[2][t] + part[3][t]) * (1.f / 2048.f);
  __syncthreads();
  if (t < 4) {
    float a = 0.f;
    for (int cc = 0; cc < 64; ++cc) a += sv[cc] * sew1[cc * 4 + t];
    hid[t] = fmaxf(a, 0.f);
  }
  __syncthreads();
  if (t < 64) {
    float a = 0.f;
#pragma unroll
    for (int h = 0; h < 4; ++h) a += hid[h] * sew2[h * 64 + t];
    y[b * 64 + t] = 1.f / (1.f + expf(-a));
  }
}

// ---------------------------------------------------------------- K4: per-point stats (f32)
__global__ void k_stats(const float* __restrict__ agg, const float* __restrict__ y,
                        float* __restrict__ ycat) {
  int t = threadIdx.x;
  int gid = blockIdx.x * 4 + (t >> 6);
  int l = t & 63;
  int b = gid >> 11, i = gid & 2047;
  float v = agg[(size_t)gid * CC + l] * y[b * 64 + l];
  float s = v, mx = v;
#pragma unroll
  for (int off = 32; off > 0; off >>= 1) {
    s += __shfl_xor(s, off);
    mx = fmaxf(mx, __shfl_xor(mx, off));
  }
  if (l == 0) {
    ycat[b * 2 * NN + i] = s * (1.f / 64.f);
    ycat[b * 2 * NN + NN + i] = mx;
  }
}

// ---------------------------------------------------------------- K5: conv7 att + add (f32 out)
__global__ void k_final(const float* __restrict__ agg, const float* __restrict__ y,
                        const float* __restrict__ ycat, const float* __restrict__ saw,
                        const float* __restrict__ x, float* __restrict__ out) {
  int e = blockIdx.x * 256 + threadIdx.x;
  int ifl = e >> 6, c = e & 63;
  int b = ifl >> 11, i = ifl & 2047;
  float a = 0.f;
#pragma unroll
  for (int w = 0; w < 7; ++w) {
    int ii = i + w - 3;
    if (ii >= 0 && ii < NN) {
      a += ycat[b * 2 * NN + ii] * saw[w];
      a += ycat[b * 2 * NN + NN + ii] * saw[7 + w];
    }
  }
  float att = 1.f / (1.f + expf(-a));
  out[e] = agg[(size_t)ifl * CC + c] * y[b * 64 + c] * att + x[(size_t)e];
}

// ----------------------------------------------------------------
extern "C" void kernel_launch(void* const* d_in, const int* in_sizes, int n_in,
                              void* d_out, int out_size, void* d_ws, size_t ws_size,
                              hipStream_t stream) {
  const float* x    = (const float*)d_in[0];
  const float* w1   = (const float*)d_in[3];
  const float* b1   = (const float*)d_in[4];
  const float* w2   = (const float*)d_in[5];
  const float* b2   = (const float*)d_in[6];
  const float* w3   = (const float*)d_in[7];
  const float* b3   = (const float*)d_in[8];
  const float* sew1 = (const float*)d_in[9];
  const float* sew2 = (const float*)d_in[10];
  const float* saw  = (const float*)d_in[11];
  float* out = (float*)d_out;

  char* ws = (char*)d_ws;
  float* sq   = (float*)(ws);                              // 131072 B
  int*   idx  = (int*)  (ws + 131072);                     // 2621440 B
  float* agg  = (float*)(ws + 131072 + 2621440);           // 8388608 B
  float* y    = (float*)(ws + 11141120);                   // 4096 B
  float* ycat = (float*)(ws + 11145216);                   // 262144 B

  k_sq   <<<128,            256, 0, stream>>>(x, sq);
  k_knn  <<<dim3(32, 16),   256, 0, stream>>>(x, sq, idx);
  k_mlp  <<<dim3(256, 16),  256, 0, stream>>>(x, idx, w1, b1, w2, b2, w3, b3, agg);
  k_se   <<<16,             256, 0, stream>>>(agg, sew1, sew2, y);
  k_stats<<<8192,           256, 0, stream>>>(agg, y, ycat);
  k_final<<<8192,           256, 0, stream>>>(agg, y, ycat, saw, x, out);
}

// Round 8
// 678.128 us; speedup vs baseline: 2.5325x; 1.1351x over previous
//
#include <hip/hip_runtime.h>

typedef unsigned int uint32;
typedef unsigned long long uint64;
typedef unsigned short ushortT;
typedef __attribute__((ext_vector_type(8))) short short8;
typedef __attribute__((ext_vector_type(4))) short short4v;
typedef __attribute__((ext_vector_type(4))) float floatx4;

#define DEV static __device__ __forceinline__

#define NN 2048
#define CC 64
#define KK 20

DEV float bf2f(ushortT h) {
  union { uint32 u; float f; } c; c.u = ((uint32)h) << 16; return c.f;
}
DEV ushortT f2bf(float f) {
  union { float f; uint32 u; } c; c.f = f;
  uint32 r = c.u + 0x7FFFu + ((c.u >> 16) & 1u);   // RNE
  return (ushortT)(r >> 16);
}
DEV void split2(float v, ushortT& h, ushortT& l) {
  h = f2bf(v);
  l = f2bf(v - bf2f(h));
}

// ---------------------------------------------------------------- K0: sq norms (f32)
__global__ void k_sq(const float* __restrict__ x, float* __restrict__ sq) {
  int p = blockIdx.x * 256 + threadIdx.x;
  const float4* row = (const float4*)(x + (size_t)p * CC);
  float s = 0.f;
#pragma unroll
  for (int q = 0; q < 16; ++q) {
    float4 v = row[q];
    s += v.x * v.x + v.y * v.y + v.z * v.z + v.w * v.w;
  }
  sq[p] = s;
}

// ---------------------------------------------------------------- K1: KNN top-20
// MFMA approx keys -> tau-filtered per-point LDS queues (cap 128 = tile size,
// no overflow possible) -> 4 owner threads/point chain-insert only accepted
// candidates into register top-20 lists (min/max swap chain). tau[p] = min over
// the 4 threads of lst[19] (provably >= global 20th key). Union of 4x20 = 80
// candidates f64-reranked cooperatively; exact top-20 written out.
__launch_bounds__(256, 2)
__global__ void k_knn(const float* __restrict__ x, const float* __restrict__ sq,
                      int* __restrict__ idxout) {
  const int b  = blockIdx.y;
  const int i0 = blockIdx.x * 64;
  const int t  = threadIdx.x;
  const int l  = t & 63, wv = t >> 6;
  const int la = l & 15, quad = l >> 4;
  const int pp = t >> 2, ss = t & 3;          // owner mapping: point, sub-slot

  __shared__ __align__(16) char sm[62720];
  ushortT (*sXi)[72]  = (ushortT(*)[72])(sm);            // 9216
  float*   sSqi       = (float*)(sm + 9216);             // 256
  float*   sSqj       = (float*)(sm + 9472);             // 512
  ushortT (*sXj)[72]  = (ushortT(*)[72])(sm + 9984);     // 18432 -> 28416
  uint32  (*sQ)[132]  = (uint32(*)[132])(sm + 28416);    // 33792 -> 62208
  int*     sCnt       = (int*)(sm + 62208);              // 256
  uint32*  sTau       = (uint32*)(sm + 62464);           // 256
  uint64  (*sK64)[81] = (uint64(*)[81])(sm);             // 41472, aliases sXi..sQ (used last)

  const float* xb = x + ((size_t)b * NN) * CC;

  for (int e = t; e < 1024; e += 256) {                  // stage Xi (bf16)
    int r = e >> 4, c4 = (e & 15) * 4;
    float4 v = ((const float4*)(xb + (size_t)(i0 + r) * CC))[e & 15];
    short4v h;
    h.x = (short)f2bf(v.x); h.y = (short)f2bf(v.y);
    h.z = (short)f2bf(v.z); h.w = (short)f2bf(v.w);
    *(short4v*)&sXi[r][c4] = h;
  }
  if (t < 64) {
    sSqi[t] = sq[b * NN + i0 + t];
    sCnt[t] = 0;
    sTau[t] = 0xFFFFFFFFu;
  }
  // stage tile 0
  for (int e = t; e < 2048; e += 256) {
    int r = e >> 4, c4 = (e & 15) * 4;
    float4 v = ((const float4*)(xb + (size_t)r * CC))[e & 15];
    short4v h;
    h.x = (short)f2bf(v.x); h.y = (short)f2bf(v.y);
    h.z = (short)f2bf(v.z); h.w = (short)f2bf(v.w);
    *(short4v*)&sXj[r][c4] = h;
  }
  if (t < 128) sSqj[t] = sq[b * NN + t];

  uint32 lst[KK];
#pragma unroll
  for (int s = 0; s < KK; ++s) lst[s] = 0xFFFFFFFFu;

  const int mt0 = (wv & 1) * 2;
  const int nt0 = (wv >> 1) * 4;

  __syncthreads();

  for (int jt = 0; jt < 16; ++jt) {
    const int j0 = jt * 128;

    floatx4 acc[2][4];
#pragma unroll
    for (int m = 0; m < 2; ++m)
#pragma unroll
      for (int n = 0; n < 4; ++n) acc[m][n] = (floatx4){0.f, 0.f, 0.f, 0.f};

#pragma unroll
    for (int ks = 0; ks < 2; ++ks) {
      int kof = ks * 32 + quad * 8;
      short8 a0 = *(const short8*)&sXi[(mt0    ) * 16 + la][kof];
      short8 a1 = *(const short8*)&sXi[(mt0 + 1) * 16 + la][kof];
#pragma unroll
      for (int n = 0; n < 4; ++n) {
        short8 bv = *(const short8*)&sXj[(nt0 + n) * 16 + la][kof];
        acc[0][n] = __builtin_amdgcn_mfma_f32_16x16x32_bf16(a0, bv, acc[0][n], 0, 0, 0);
        acc[1][n] = __builtin_amdgcn_mfma_f32_16x16x32_bf16(a1, bv, acc[1][n], 0, 0, 0);
      }
    }

    // filter vs tau + batched queue push (per il group of 4 candidates)
#pragma unroll
    for (int m = 0; m < 2; ++m) {
#pragma unroll
      for (int rg = 0; rg < 4; ++rg) {
        int il = (mt0 + m) * 16 + quad * 4 + rg;
        float di = sSqi[il];
        uint32 tau = sTau[il];
        uint32 key[4]; bool a[4]; int na = 0;
#pragma unroll
        for (int n = 0; n < 4; ++n) {
          int jl = (nt0 + n) * 16 + la;
          float d = fmaxf(di + sSqj[jl] - 2.0f * acc[m][n][rg], 0.f);
          key[n] = (__float_as_uint(d) & 0xFFFFF800u) | (uint32)(j0 + jl);
          a[n] = key[n] < tau;
          na += a[n] ? 1 : 0;
        }
        if (na) {
          int base = atomicAdd(&sCnt[il], na);
#pragma unroll
          for (int n = 0; n < 4; ++n)
            if (a[n]) sQ[il][base++] = key[n];
        }
      }
    }
    __syncthreads();

    // drain own quarter of the queue; overlap staging of next tile
    {
      int cn = sCnt[pp];
      for (int q = ss; q < cn; q += 4) {
        uint32 c = sQ[pp][q];
        if (c < lst[KK - 1]) {
          uint32 cur = c;
#pragma unroll
          for (int s = 0; s < KK; ++s) {
            uint32 lo = min(lst[s], cur);
            cur = max(lst[s], cur);
            lst[s] = lo;
          }
        }
      }
    }
    if (jt < 15) {
      const int jn = (jt + 1) * 128;
      for (int e = t; e < 2048; e += 256) {
        int r = e >> 4, c4 = (e & 15) * 4;
        float4 v = ((const float4*)(xb + (size_t)(jn + r) * CC))[e & 15];
        short4v h;
        h.x = (short)f2bf(v.x); h.y = (short)f2bf(v.y);
        h.z = (short)f2bf(v.z); h.w = (short)f2bf(v.w);
        *(short4v*)&sXj[r][c4] = h;
      }
      if (t < 128) sSqj[t] = sq[b * NN + jn + t];
    }
    atomicMin(&sTau[pp], lst[KK - 1]);
    if (ss == 0) sCnt[pp] = 0;
    __syncthreads();
  }

  // dump union (80 candidates/point) into alias region
#pragma unroll
  for (int q = 0; q < KK; ++q)
    sK64[pp][ss * KK + q] = (uint64)lst[q];
  __syncthreads();

  // cooperative exact-f64 rerank: 16 groups x 16 lanes; 64x80 pairs
  {
    const int grp = t >> 4;
    const int lg  = t & 15;
    for (int p = 0; p < 64; ++p) {
      const float* xi = xb + (size_t)(i0 + p) * CC;
      float4 vi = ((const float4*)xi)[lg];
      for (int q = grp; q < 80; q += 16) {
        int j = (int)((uint32)sK64[p][q] & 2047u);
        float4 vj = ((const float4*)(xb + (size_t)j * CC))[lg];
        double d;
        {
          double d0 = (double)vi.x - (double)vj.x;
          double d1 = (double)vi.y - (double)vj.y;
          double d2 = (double)vi.z - (double)vj.z;
          double d3 = (double)vi.w - (double)vj.w;
          d = d0 * d0 + d1 * d1 + d2 * d2 + d3 * d3;
        }
#pragma unroll
        for (int off = 8; off > 0; off >>= 1)
          d += __shfl_xor(d, off, 16);
        if (lg == 0) {
          uint64 bits = (uint64)__double_as_longlong(d);  // d >= 0: order-preserving
          sK64[p][q] = (bits & ~2047ULL) | (uint64)j;
        }
      }
    }
  }
  __syncthreads();

  if (ss == 0) {                                         // 64 threads spread over 4 waves
    uint64 bl[KK];
#pragma unroll
    for (int s = 0; s < KK; ++s) bl[s] = ~0ULL;
    for (int q = 0; q < 80; ++q) {
      uint64 c = sK64[pp][q];
      if (c < bl[KK - 1]) {
        uint64 cur = c;
#pragma unroll
        for (int s = 0; s < KK; ++s) {
          uint64 lo = bl[s] < cur ? bl[s] : cur;
          cur = bl[s] < cur ? cur : bl[s];
          bl[s] = lo;
        }
      }
    }
    size_t base = ((size_t)(b * NN + i0 + pp)) * KK;
#pragma unroll
    for (int s = 0; s < KK; ++s) idxout[base + s] = (int)(bl[s] & 2047ULL);
  }
}

// ---------------------------------------------------------------- K2: edge MLP + max-agg (near-f32-exact)
__launch_bounds__(256, 1)
__global__ void k_mlp(const float* __restrict__ x, const int* __restrict__ idx,
                      const float* __restrict__ w1, const float* __restrict__ b1,
                      const float* __restrict__ w2, const float* __restrict__ b2,
                      const float* __restrict__ w3, const float* __restrict__ b3,
                      float* __restrict__ agg) {
  const int b  = blockIdx.y;
  const int i0 = blockIdx.x * 8;
  const int t  = threadIdx.x;
  const int l  = t & 63, wv = t >> 6;
  const int la = l & 15, quad = l >> 4;
  const int wm = wv >> 1, wn = wv & 1;

  __shared__ __align__(16) char sm[152448];
  ushortT (*sW1)[136] = (ushortT(*)[136])(sm + 0);
  ushortT (*sW2)[72]  = (ushortT(*)[72])(sm + 17408);
  ushortT (*sW3)[72]  = (ushortT(*)[72])(sm + 26624);
  ushortT (*sXi)[72]  = (ushortT(*)[72])(sm + 35840);
  ushortT (*sDH)[72]  = (ushortT(*)[72])(sm + 58880);
  ushortT (*sDL)[72]  = (ushortT(*)[72])(sm + 81920);
  ushortT (*sH1H)[72] = (ushortT(*)[72])(sm + 104960);
  ushortT (*sH1L)[72] = (ushortT(*)[72])(sm + 128000);
  float   (*sH3)[68]  = (float(*)[68])  (sm + 104960);
  float* sB1 = (float*)(sm + 151040);
  float* sB2 = (float*)(sm + 151296);
  float* sB3 = (float*)(sm + 151552);
  int*   sJ  = (int*)  (sm + 151808);

  for (int e = t; e < 8192; e += 256) {
    int k = e >> 6, n = e & 63;
    sW1[n][k] = f2bf(w1[e]);
  }
  for (int e = t; e < 4096; e += 256) {
    int k = e >> 6, n = e & 63;
    sW2[n][k] = f2bf(w2[e]);
    sW3[n][k] = f2bf(w3[e]);
  }
  if (t < 64) { sB1[t] = b1[t]; sB2[t] = b2[t]; sB3[t] = b3[t]; }
  if (t < 160) {
    int p = t / 20, kk = t - p * 20;
    int v = idx[((size_t)(b * NN + i0 + p)) * KK + kk];
    v = v < 0 ? 0 : (v > (NN - 1) ? (NN - 1) : v);
    sJ[t] = v;
  }
  __syncthreads();

  const float* xb = x + ((size_t)b * NN) * CC;
  for (int e = t; e < 2560; e += 256) {
    int r = e >> 4, c4g = e & 15, c4 = c4g * 4;
    int p = r / 20;
    float4 vi = ((const float4*)(xb + (size_t)(i0 + p) * CC))[c4g];
    float4 vj = ((const float4*)(xb + (size_t)sJ[r] * CC))[c4g];
    short4v hi, dh, dl;
    ushortT hh, ll;
    hi.x = (short)f2bf(vi.x); hi.y = (short)f2bf(vi.y);
    hi.z = (short)f2bf(vi.z); hi.w = (short)f2bf(vi.w);
    split2(vj.x - vi.x, hh, ll); dh.x = (short)hh; dl.x = (short)ll;
    split2(vj.y - vi.y, hh, ll); dh.y = (short)hh; dl.y = (short)ll;
    split2(vj.z - vi.z, hh, ll); dh.z = (short)hh; dl.z = (short)ll;
    split2(vj.w - vi.w, hh, ll); dh.w = (short)hh; dl.w = (short)ll;
    *(short4v*)&sXi[r][c4] = hi;
    *(short4v*)&sDH[r][c4] = dh;
    *(short4v*)&sDL[r][c4] = dl;
  }
  __syncthreads();

  // ---- layer 1
  {
    short8 bA[2][2], bB[2][2];
#pragma unroll
    for (int n2 = 0; n2 < 2; ++n2)
#pragma unroll
      for (int ks = 0; ks < 2; ++ks) {
        bA[n2][ks] = *(const short8*)&sW1[(wn * 2 + n2) * 16 + la][ks * 32 + quad * 8];
        bB[n2][ks] = *(const short8*)&sW1[(wn * 2 + n2) * 16 + la][64 + ks * 32 + quad * 8];
      }
    for (int m5 = 0; m5 < 5; ++m5) {
      int mt = wm * 5 + m5;
      floatx4 a0 = (floatx4){0.f,0.f,0.f,0.f}, a1 = (floatx4){0.f,0.f,0.f,0.f};
#pragma unroll
      for (int ks = 0; ks < 2; ++ks) {
        int kof = ks * 32 + quad * 8;
        short8 aXi = *(const short8*)&sXi[mt * 16 + la][kof];
        short8 aDH = *(const short8*)&sDH[mt * 16 + la][kof];
        short8 aDL = *(const short8*)&sDL[mt * 16 + la][kof];
        a0 = __builtin_amdgcn_mfma_f32_16x16x32_bf16(aXi, bA[0][ks], a0, 0, 0, 0);
        a0 = __builtin_amdgcn_mfma_f32_16x16x32_bf16(aDH, bB[0][ks], a0, 0, 0, 0);
        a0 = __builtin_amdgcn_mfma_f32_16x16x32_bf16(aDL, bB[0][ks], a0, 0, 0, 0);
        a1 = __builtin_amdgcn_mfma_f32_16x16x32_bf16(aXi, bA[1][ks], a1, 0, 0, 0);
        a1 = __builtin_amdgcn_mfma_f32_16x16x32_bf16(aDH, bB[1][ks], a1, 0, 0, 0);
        a1 = __builtin_amdgcn_mfma_f32_16x16x32_bf16(aDL, bB[1][ks], a1, 0, 0, 0);
      }
      int n0c = (wn * 2) * 16 + la, n1c = (wn * 2 + 1) * 16 + la;
#pragma unroll
      for (int rg = 0; rg < 4; ++rg) {
        int r = mt * 16 + quad * 4 + rg;
        ushortT hh, ll;
        split2(fmaxf(a0[rg] + sB1[n0c], 0.f), hh, ll);
        sH1H[r][n0c] = hh; sH1L[r][n0c] = ll;
        split2(fmaxf(a1[rg] + sB1[n1c], 0.f), hh, ll);
        sH1H[r][n1c] = hh; sH1L[r][n1c] = ll;
      }
    }
  }
  __syncthreads();

  // ---- layer 2
  ushortT (*sH2H)[72] = sXi;
  ushortT (*sH2L)[72] = sDH;
  {
    short8 bf[2][2];
#pragma unroll
    for (int n2 = 0; n2 < 2; ++n2)
#pragma unroll
      for (int ks = 0; ks < 2; ++ks)
        bf[n2][ks] = *(const short8*)&sW2[(wn * 2 + n2) * 16 + la][ks * 32 + quad * 8];
    for (int m5 = 0; m5 < 5; ++m5) {
      int mt = wm * 5 + m5;
      floatx4 a0 = (floatx4){0.f,0.f,0.f,0.f}, a1 = (floatx4){0.f,0.f,0.f,0.f};
#pragma unroll
      for (int ks = 0; ks < 2; ++ks) {
        int kof = ks * 32 + quad * 8;
        short8 aH = *(const short8*)&sH1H[mt * 16 + la][kof];
        short8 aL = *(const short8*)&sH1L[mt * 16 + la][kof];
        a0 = __builtin_amdgcn_mfma_f32_16x16x32_bf16(aH, bf[0][ks], a0, 0, 0, 0);
        a0 = __builtin_amdgcn_mfma_f32_16x16x32_bf16(aL, bf[0][ks], a0, 0, 0, 0);
        a1 = __builtin_amdgcn_mfma_f32_16x16x32_bf16(aH, bf[1][ks], a1, 0, 0, 0);
        a1 = __builtin_amdgcn_mfma_f32_16x16x32_bf16(aL, bf[1][ks], a1, 0, 0, 0);
      }
      int n0c = (wn * 2) * 16 + la, n1c = (wn * 2 + 1) * 16 + la;
#pragma unroll
      for (int rg = 0; rg < 4; ++rg) {
        int r = mt * 16 + quad * 4 + rg;
        ushortT hh, ll;
        split2(fmaxf(a0[rg] + sB2[n0c], 0.f), hh, ll);
        sH2H[r][n0c] = hh; sH2L[r][n0c] = ll;
        split2(fmaxf(a1[rg] + sB2[n1c], 0.f), hh, ll);
        sH2H[r][n1c] = hh; sH2L[r][n1c] = ll;
      }
    }
  }
  __syncthreads();

  // ---- layer 3
  {
    short8 bf[2][2];
#pragma unroll
    for (int n2 = 0; n2 < 2; ++n2)
#pragma unroll
      for (int ks = 0; ks < 2; ++ks)
        bf[n2][ks] = *(const short8*)&sW3[(wn * 2 + n2) * 16 + la][ks * 32 + quad * 8];
    for (int m5 = 0; m5 < 5; ++m5) {
      int mt = wm * 5 + m5;
      floatx4 a0 = (floatx4){0.f,0.f,0.f,0.f}, a1 = (floatx4){0.f,0.f,0.f,0.f};
#pragma unroll
      for (int ks = 0; ks < 2; ++ks) {
        int kof = ks * 32 + quad * 8;
        short8 aH = *(const short8*)&sH2H[mt * 16 + la][kof];
        short8 aL = *(const short8*)&sH2L[mt * 16 + la][kof];
        a0 = __builtin_amdgcn_mfma_f32_16x16x32_bf16(aH, bf[0][ks], a0, 0, 0, 0);
        a0 = __builtin_amdgcn_mfma_f32_16x16x32_bf16(aL, bf[0][ks], a0, 0, 0, 0);
        a1 = __builtin_amdgcn_mfma_f32_16x16x32_bf16(aH, bf[1][ks], a1, 0, 0, 0);
        a1 = __builtin_amdgcn_mfma_f32_16x16x32_bf16(aL, bf[1][ks], a1, 0, 0, 0);
      }
      int n0c = (wn * 2) * 16 + la, n1c = (wn * 2 + 1) * 16 + la;
#pragma unroll
      for (int rg = 0; rg < 4; ++rg) {
        int r = mt * 16 + quad * 4 + rg;
        sH3[r][n0c] = a0[rg] + sB3[n0c];
        sH3[r][n1c] = a1[rg] + sB3[n1c];
      }
    }
  }
  __syncthreads();

  for (int e = t; e < 512; e += 256) {
    int p = e >> 6, c = e & 63;
    float m = -3.0e38f;
#pragma unroll
    for (int k = 0; k < KK; ++k) m = fmaxf(m, sH3[p * 20 + k][c]);
    agg[((size_t)(b * NN + i0 + p)) * CC + c] = m;
  }
}

// ---------------------------------------------------------------- K3: SE (f32)
__global__ void k_se(const float* __restrict__ agg, const float* __restrict__ sew1,
                     const float* __restrict__ sew2, float* __restrict__ y) {
  int b = blockIdx.x, t = threadIdx.x;
  int c = t & 63, q = t >> 6;
  __shared__ float part[4][64];
  __shared__ float sv[64];
  __shared__ float hid[4];
  const float* ab = agg + ((size_t)b * NN) * CC;
  float s = 0.f;
  for (int n = q * 512; n < q * 512 + 512; ++n) s += ab[(size_t)n * CC + c];
  part[q][c] = s;
  __syncthreads();
  if (t < 64) sv[t] = (part[0][t] + part[1][t] + part[2][t] + part[3][t]) * (1.f / 2048.f);
  __syncthreads();
  if (t < 4) {
    float a = 0.f;
    for (int cc = 0; cc < 64; ++cc) a += sv[cc] * sew1[cc * 4 + t];
    hid[t] = fmaxf(a, 0.f);
  }
  __syncthreads();
  if (t < 64) {
    float a = 0.f;
#pragma unroll
    for (int h = 0; h < 4; ++h) a += hid[h] * sew2[h * 64 + t];
    y[b * 64 + t] = 1.f / (1.f + expf(-a));
  }
}

// ---------------------------------------------------------------- K4: per-point stats (f32)
__global__ void k_stats(const float* __restrict__ agg, const float* __restrict__ y,
                        float* __restrict__ ycat) {
  int t = threadIdx.x;
  int gid = blockIdx.x * 4 + (t >> 6);
  int l = t & 63;
  int b = gid >> 11, i = gid & 2047;
  float v = agg[(size_t)gid * CC + l] * y[b * 64 + l];
  float s = v, mx = v;
#pragma unroll
  for (int off = 32; off > 0; off >>= 1) {
    s += __shfl_xor(s, off);
    mx = fmaxf(mx, __shfl_xor(mx, off));
  }
  if (l == 0) {
    ycat[b * 2 * NN + i] = s * (1.f / 64.f);
    ycat[b * 2 * NN + NN + i] = mx;
  }
}

// ---------------------------------------------------------------- K5: conv7 att + add (f32 out)
__global__ void k_final(const float* __restrict__ agg, const float* __restrict__ y,
                        const float* __restrict__ ycat, const float* __restrict__ saw,
                        const float* __restrict__ x, float* __restrict__ out) {
  int e = blockIdx.x * 256 + threadIdx.x;
  int ifl = e >> 6, c = e & 63;
  int b = ifl >> 11, i = ifl & 2047;
  float a = 0.f;
#pragma unroll
  for (int w = 0; w < 7; ++w) {
    int ii = i + w - 3;
    if (ii >= 0 && ii < NN) {
      a += ycat[b * 2 * NN + ii] * saw[w];
      a += ycat[b * 2 * NN + NN + ii] * saw[7 + w];
    }
  }
  float att = 1.f / (1.f + expf(-a));
  out[e] = agg[(size_t)ifl * CC + c] * y[b * 64 + c] * att + x[(size_t)e];
}

// ----------------------------------------------------------------
extern "C" void kernel_launch(void* const* d_in, const int* in_sizes, int n_in,
                              void* d_out, int out_size, void* d_ws, size_t ws_size,
                              hipStream_t stream) {
  const float* x    = (const float*)d_in[0];
  const float* w1   = (const float*)d_in[3];
  const float* b1   = (const float*)d_in[4];
  const float* w2   = (const float*)d_in[5];
  const float* b2   = (const float*)d_in[6];
  const float* w3   = (const float*)d_in[7];
  const float* b3   = (const float*)d_in[8];
  const float* sew1 = (const float*)d_in[9];
  const float* sew2 = (const float*)d_in[10];
  const float* saw  = (const float*)d_in[11];
  float* out = (float*)d_out;

  char* ws = (char*)d_ws;
  float* sq   = (float*)(ws);                              // 131072 B
  int*   idx  = (int*)  (ws + 131072);                     // 2621440 B
  float* agg  = (float*)(ws + 131072 + 2621440);           // 8388608 B
  float* y    = (float*)(ws + 11141120);                   // 4096 B
  float* ycat = (float*)(ws + 11145216);                   // 262144 B

  k_sq   <<<128,            256, 0, stream>>>(x, sq);
  k_knn  <<<dim3(32, 16),   256, 0, stream>>>(x, sq, idx);
  k_mlp  <<<dim3(256, 16),  256, 0, stream>>>(x, idx, w1, b1, w2, b2, w3, b3, agg);
  k_se   <<<16,             256, 0, stream>>>(agg, sew1, sew2, y);
  k_stats<<<8192,           256, 0, stream>>>(agg, y, ycat);
  k_final<<<8192,           256, 0, stream>>>(agg, y, ycat, saw, x, out);
}